// Round 1
// baseline (519.389 us; speedup 1.0000x reference)
//
#include <hip/hip_runtime.h>
#include <hip/hip_fp16.h>

#define BATCH 4
#define CH 256
#define HW 4096
#define K_TOP 115
#define COLS 16
#define CAND 128
#define PADROW 4104  // 4096 + 8 halfword pad -> row stride 2052 words, stride%32=4

typedef __attribute__((ext_vector_type(8))) short short8;
typedef __attribute__((ext_vector_type(4))) float f32x4;

__device__ __forceinline__ unsigned short f32_to_bf16(float f) {
  union { float f; unsigned int u; } v; v.f = f;
  unsigned int r = v.u + 0x7fffu + ((v.u >> 16) & 1u);
  return (unsigned short)(r >> 16);
}

__device__ __forceinline__ unsigned int f16key(unsigned short h) {
  // monotone map: f16 bits -> u16 key, ascending float order == ascending key
  return (h & 0x8000u) ? (unsigned int)((unsigned short)~h)
                       : (unsigned int)(h | 0x8000u);
}

__device__ __forceinline__ unsigned short key2f16(unsigned short k) {
  return (k & 0x8000u) ? (unsigned short)(k ^ 0x8000u)
                       : (unsigned short)(~k);
}

// ---------- kernel 1a: rn[b][p] = 1 / max(||x[b,:,p]||, eps) ----------
__global__ void norms_kernel(const float* __restrict__ x, float* __restrict__ rn) {
  int b = blockIdx.x >> 4;                       // 16 blocks per batch
  int p = ((blockIdx.x & 15) << 8) + threadIdx.x;
  const float* xb = x + (size_t)b * CH * HW + p;
  float ss = 0.f;
  #pragma unroll 8
  for (int c = 0; c < CH; ++c) { float v = xb[(size_t)c * HW]; ss += v * v; }
  rn[b * HW + p] = 1.0f / fmaxf(sqrtf(ss), 1e-12f);
}

// ---------- kernel 1b: xnT[b][p][c] = bf16(x[b][c][p] * rn[b][p]) ----------
__global__ void transpose_kernel(const float* __restrict__ x, const float* __restrict__ rn,
                                 unsigned short* __restrict__ xnT) {
  __shared__ float tile[64][65];
  int blk = blockIdx.x;
  int b = blk >> 8;           // 4 batches
  int rem = blk & 255;        // 4 channel tiles x 64 pixel tiles
  int c0 = (rem >> 6) << 6;
  int p0 = (rem & 63) << 6;
  for (int idx = threadIdx.x; idx < 64 * 64; idx += blockDim.x) {
    int c = idx >> 6, p = idx & 63;
    tile[c][p] = x[((size_t)b * CH + c0 + c) * HW + p0 + p];
  }
  __syncthreads();
  for (int idx = threadIdx.x; idx < 64 * 64; idx += blockDim.x) {
    int p = idx >> 6, c = idx & 63;
    xnT[((size_t)b * HW + p0 + p) * CH + c0 + c] =
        f32_to_bf16(tile[c][p] * rn[b * HW + p0 + p]);
  }
}

// ---------- kernel 2: fused Gram panel (MFMA) + top-115 select ----------
struct K2Smem {
  unsigned short colvals[COLS][PADROW];  // raw dot (before /256) as f16 bits
  unsigned int   hist[COLS][256];
  unsigned short cand[COLS][CAND];
  unsigned int   cnt[COLS];
  unsigned int   tkey[COLS];
  unsigned int   ngr[COLS];
  unsigned int   bsel[COLS];
};

__launch_bounds__(512, 1)
__global__ void corr_topk_kernel(const unsigned short* __restrict__ xnT,
                                 float* __restrict__ out) {
  __shared__ K2Smem s;
  const int tid = threadIdx.x;
  const int b  = blockIdx.x >> 8;
  const int j0 = (blockIdx.x & 255) * COLS;
  const short8* x8 = (const short8*)(xnT + (size_t)b * HW * CH);

  const int lane = tid & 63;
  const int w    = tid >> 6;   // 8 waves
  const int lr   = lane & 15;  // fragment row/col index
  const int lk   = lane >> 4;  // k-group

  // B fragments: pixel j0+lr, channels kk*32 + lk*8 .. +8 (8 consecutive bf16 = 16B)
  short8 bfrag[8];
  #pragma unroll
  for (int kk = 0; kk < 8; ++kk)
    bfrag[kk] = x8[(j0 + lr) * 32 + kk * 4 + lk];

  // ---- GEMM phase: each wave sweeps i-tiles of 16 rows ----
  for (int it = w; it < 256; it += 8) {
    const int i0 = it * 16;
    f32x4 acc = {0.f, 0.f, 0.f, 0.f};
    #pragma unroll
    for (int kk = 0; kk < 8; ++kk) {
      short8 afrag = x8[(i0 + lr) * 32 + kk * 4 + lk];
      acc = __builtin_amdgcn_mfma_f32_16x16x32_bf16(afrag, bfrag[kk], acc, 0, 0, 0);
    }
    // C/D layout (m89): lane holds D[row=(lane>>4)*4+r][col=lane&15]
    // row -> i (source pixel), col -> j (dest pixel)
    unsigned short h0 = __half_as_ushort(__float2half(acc[0]));
    unsigned short h1 = __half_as_ushort(__float2half(acc[1]));
    unsigned short h2 = __half_as_ushort(__float2half(acc[2]));
    unsigned short h3 = __half_as_ushort(__float2half(acc[3]));
    unsigned int* dst = (unsigned int*)&s.colvals[lr][i0 + lk * 4];
    dst[0] = (unsigned int)h0 | ((unsigned int)h1 << 16);
    dst[1] = (unsigned int)h2 | ((unsigned int)h3 << 16);
  }
  __syncthreads();

  // ---- selection phase: 32 threads per column ----
  const int col = tid >> 5;
  const int tl  = tid & 31;

  // pass 1: histogram of high byte of sortable key
  for (int k = tid; k < COLS * 256; k += 512) ((unsigned int*)s.hist)[k] = 0;
  __syncthreads();
  for (int i = tl; i < HW; i += 32) {
    unsigned int key = f16key(s.colvals[col][i]);
    atomicAdd(&s.hist[col][key >> 8], 1u);
  }
  __syncthreads();
  if (tid < COLS) {
    int cum = 0, bin = 255;
    for (;; --bin) {
      int c = (int)s.hist[tid][bin];
      if (cum + c >= K_TOP || bin == 0) break;
      cum += c;
    }
    s.bsel[tid] = (unsigned int)bin;
    s.ngr[tid]  = (unsigned int)cum;  // count with key >= (bin+1)<<8
  }
  __syncthreads();

  // pass 2: histogram of low byte within selected bin
  for (int k = tid; k < COLS * 256; k += 512) ((unsigned int*)s.hist)[k] = 0;
  __syncthreads();
  {
    unsigned int bs = s.bsel[col];
    for (int i = tl; i < HW; i += 32) {
      unsigned int key = f16key(s.colvals[col][i]);
      if ((key >> 8) == bs) atomicAdd(&s.hist[col][key & 255], 1u);
    }
  }
  __syncthreads();
  if (tid < COLS) {
    int cum = (int)s.ngr[tid], lo = 255;
    for (;; --lo) {
      int c = (int)s.hist[tid][lo];
      if (cum + c >= K_TOP || lo == 0) break;
      cum += c;
    }
    s.tkey[tid] = (s.bsel[tid] << 8) | (unsigned int)lo;  // exact threshold key
    s.ngr[tid]  = (unsigned int)cum;                      // # keys strictly > tkey (<115)
  }
  __syncthreads();

  // gather: fill cand with threshold key, then scatter strictly-greater keys
  for (int k = tid; k < COLS * CAND; k += 512)
    s.cand[k >> 7][k & 127] = (unsigned short)s.tkey[k >> 7];
  if (tid < COLS) s.cnt[tid] = 0;
  __syncthreads();
  {
    unsigned int tk = s.tkey[col];
    for (int i = tl; i < HW; i += 32) {
      unsigned int key = f16key(s.colvals[col][i]);
      if (key > tk) {
        unsigned int pos = atomicAdd(&s.cnt[col], 1u);
        s.cand[col][pos] = (unsigned short)key;  // pos < 115 guaranteed
      }
    }
  }

  // bitonic sort 128 keys per column, descending
  for (int size = 2; size <= CAND; size <<= 1) {
    for (int stride = size >> 1; stride > 0; stride >>= 1) {
      __syncthreads();
      for (int q = tl; q < CAND / 2; q += 32) {
        int i = (q % stride) + 2 * stride * (q / stride);
        int j = i + stride;
        unsigned short a = s.cand[col][i];
        unsigned short bmm = s.cand[col][j];
        bool desc = ((i & size) == 0);
        if (desc ? (a < bmm) : (a > bmm)) {
          s.cand[col][i] = bmm;
          s.cand[col][j] = a;
        }
      }
    }
  }
  __syncthreads();

  // output: out[b][k][j] = f32(cand[col][k]) / 256
  for (int k = tl; k < K_TOP; k += 32) {
    unsigned short hb = key2f16(s.cand[col][k]);
    float v = __half2float(__ushort_as_half(hb)) * (1.0f / 256.0f);
    out[((size_t)b * K_TOP + k) * HW + j0 + col] = v;
  }
}

extern "C" void kernel_launch(void* const* d_in, const int* in_sizes, int n_in,
                              void* d_out, int out_size, void* d_ws, size_t ws_size,
                              hipStream_t stream) {
  (void)in_sizes; (void)n_in; (void)out_size; (void)ws_size;
  const float* x = (const float*)d_in[0];
  float* out = (float*)d_out;
  float* rn = (float*)d_ws;                                   // 16384 f32 = 64 KB
  unsigned short* xnT = (unsigned short*)((char*)d_ws + 65536);  // 8 MB bf16

  norms_kernel<<<64, 256, 0, stream>>>(x, rn);
  transpose_kernel<<<1024, 256, 0, stream>>>(x, rn, xnT);
  corr_topk_kernel<<<1024, 512, 0, stream>>>(xnT, out);
}

// Round 2
// 365.204 us; speedup vs baseline: 1.4222x; 1.4222x over previous
//
#include <hip/hip_runtime.h>
#include <hip/hip_fp16.h>

#define BATCH 4
#define CH 256
#define HW 4096
#define K_TOP 115
#define COLS 16
#define CAND 128

typedef __attribute__((ext_vector_type(8))) short short8;
typedef __attribute__((ext_vector_type(4))) float f32x4;

__device__ __forceinline__ unsigned short f32_to_bf16(float f) {
  union { float f; unsigned int u; } v; v.f = f;
  unsigned int r = v.u + 0x7fffu + ((v.u >> 16) & 1u);
  return (unsigned short)(r >> 16);
}

__device__ __forceinline__ unsigned int f16key(unsigned short h) {
  // monotone map: f16 bits -> u16 key, ascending float order == ascending key
  return (h & 0x8000u) ? (unsigned int)((unsigned short)~h)
                       : (unsigned int)(h | 0x8000u);
}

__device__ __forceinline__ unsigned short key2f16(unsigned short k) {
  return (k & 0x8000u) ? (unsigned short)(k ^ 0x8000u)
                       : (unsigned short)(~k);
}

// ---------- kernel 1a: rn[b][p] = 1 / max(||x[b,:,p]||, eps) ----------
__global__ void norms_kernel(const float* __restrict__ x, float* __restrict__ rn) {
  int b = blockIdx.x >> 4;
  int p = ((blockIdx.x & 15) << 8) + threadIdx.x;
  const float* xb = x + (size_t)b * CH * HW + p;
  float ss = 0.f;
  #pragma unroll 8
  for (int c = 0; c < CH; ++c) { float v = xb[(size_t)c * HW]; ss += v * v; }
  rn[b * HW + p] = 1.0f / fmaxf(sqrtf(ss), 1e-12f);
}

// ---------- kernel 1b: xnT[b][p][c] = bf16(x[b][c][p] * rn[b][p]) ----------
__global__ void transpose_kernel(const float* __restrict__ x, const float* __restrict__ rn,
                                 unsigned short* __restrict__ xnT) {
  __shared__ float tile[64][65];
  int blk = blockIdx.x;
  int b = blk >> 8;
  int rem = blk & 255;
  int c0 = (rem >> 6) << 6;
  int p0 = (rem & 63) << 6;
  for (int idx = threadIdx.x; idx < 64 * 64; idx += blockDim.x) {
    int c = idx >> 6, p = idx & 63;
    tile[c][p] = x[((size_t)b * CH + c0 + c) * HW + p0 + p];
  }
  __syncthreads();
  for (int idx = threadIdx.x; idx < 64 * 64; idx += blockDim.x) {
    int p = idx >> 6, c = idx & 63;
    xnT[((size_t)b * HW + p0 + p) * CH + c0 + c] =
        f32_to_bf16(tile[c][p] * rn[b * HW + p0 + p]);
  }
}

// ---------- kernel 2: Gram panel (MFMA, keys in regs) + binary-search top-115 ----------
struct K2Smem {
  unsigned int   swcnt[2][8][COLS];   // per-wave partial counts, double-buffered
  unsigned int   tcol[COLS];          // threshold key per column
  unsigned int   cnt[COLS];
  unsigned short cand[COLS][CAND];
};

__launch_bounds__(512, 4)
__global__ void corr_topk_kernel(const unsigned short* __restrict__ xnT,
                                 float* __restrict__ out) {
  __shared__ K2Smem s;
  const int tid = threadIdx.x;
  const int b  = blockIdx.x >> 8;
  const int j0 = (blockIdx.x & 255) * COLS;
  const short8* x8 = (const short8*)(xnT + (size_t)b * HW * CH);

  const int lane = tid & 63;
  const int w    = tid >> 6;   // 8 waves
  const int lr   = lane & 15;  // fragment row/col index
  const int lk   = lane >> 4;  // k-group

  // B fragments: pixel j0+lr, channels kk*32 + lk*8 .. +8
  short8 bfrag[8];
  #pragma unroll
  for (int kk = 0; kk < 8; ++kk)
    bfrag[kk] = x8[(j0 + lr) * 32 + kk * 4 + lk];

  // ---- GEMM phase: wave w computes i-tiles w, w+8, ..., keys stay in regs ----
  // Lane owns column j0+lr; rows i0 + lk*4 + r (C/D layout per m89).
  unsigned int kreg[64];
  #pragma unroll
  for (int t = 0; t < 32; ++t) {
    const int i0 = (w + 8 * t) * 16;
    f32x4 acc = {0.f, 0.f, 0.f, 0.f};
    #pragma unroll
    for (int kk = 0; kk < 8; ++kk) {
      short8 afrag = x8[(i0 + lr) * 32 + kk * 4 + lk];
      acc = __builtin_amdgcn_mfma_f32_16x16x32_bf16(afrag, bfrag[kk], acc, 0, 0, 0);
    }
    unsigned int k0 = f16key(__half_as_ushort(__float2half(acc[0])));
    unsigned int k1 = f16key(__half_as_ushort(__float2half(acc[1])));
    unsigned int k2 = f16key(__half_as_ushort(__float2half(acc[2])));
    unsigned int k3 = f16key(__half_as_ushort(__float2half(acc[3])));
    kreg[2 * t]     = k0 | (k1 << 16);
    kreg[2 * t + 1] = k2 | (k3 << 16);
  }

  // ---- binary search for per-column 115th-largest key ----
  // f(v) = #{key >= v} over the column's 4096 keys (32 lanes x 128 each).
  unsigned int lo = 0;
  for (int bit = 15; bit >= 0; --bit) {
    const unsigned int m = lo | (1u << bit);
    int c = 0;
    #pragma unroll
    for (int r = 0; r < 64; ++r) {
      c += ((kreg[r] & 0xffffu) >= m);
      c += ((kreg[r] >> 16) >= m);
    }
    c += __shfl_xor(c, 16);
    c += __shfl_xor(c, 32);
    const int buf = bit & 1;
    if (lane < 16) s.swcnt[buf][w][lane] = (unsigned int)c;
    __syncthreads();
    int tot = 0;
    #pragma unroll
    for (int ww = 0; ww < 8; ++ww) tot += (int)s.swcnt[buf][ww][lr];
    if (tot >= K_TOP) lo = m;
  }
  // lo = max v with f(v) >= 115  => exact threshold key; #{key > lo} <= 114.

  if (w == 0 && lane < 16) { s.tcol[lane] = lo; s.cnt[lane] = 0; }
  __syncthreads();

  // prefill candidate list with the threshold key
  for (int k = tid; k < COLS * CAND; k += 512)
    s.cand[k >> 7][k & (CAND - 1)] = (unsigned short)s.tcol[k >> 7];
  __syncthreads();

  // scatter strictly-greater keys (rare -> cheap atomics)
  #pragma unroll
  for (int r = 0; r < 64; ++r) {
    unsigned int p = kreg[r];
    unsigned int a = p & 0xffffu;
    unsigned int bb = p >> 16;
    if (a > lo) {
      unsigned int pos = atomicAdd(&s.cnt[lr], 1u);
      s.cand[lr][pos] = (unsigned short)a;
    }
    if (bb > lo) {
      unsigned int pos = atomicAdd(&s.cnt[lr], 1u);
      s.cand[lr][pos] = (unsigned short)bb;
    }
  }

  // ---- bitonic sort 128 keys per column, descending ----
  const int col = tid >> 5;
  const int tl  = tid & 31;
  for (int size = 2; size <= CAND; size <<= 1) {
    for (int stride = size >> 1; stride > 0; stride >>= 1) {
      __syncthreads();
      for (int q = tl; q < CAND / 2; q += 32) {
        int i = (q % stride) + 2 * stride * (q / stride);
        int j = i + stride;
        unsigned short a = s.cand[col][i];
        unsigned short bmm = s.cand[col][j];
        bool desc = ((i & size) == 0);
        if (desc ? (a < bmm) : (a > bmm)) {
          s.cand[col][i] = bmm;
          s.cand[col][j] = a;
        }
      }
    }
  }
  __syncthreads();

  // output: out[b][k][j] = f32(cand[col][k]) / 256
  for (int k = tl; k < K_TOP; k += 32) {
    unsigned short hb = key2f16(s.cand[col][k]);
    float v = __half2float(__ushort_as_half(hb)) * (1.0f / 256.0f);
    out[((size_t)b * K_TOP + k) * HW + j0 + col] = v;
  }
}

extern "C" void kernel_launch(void* const* d_in, const int* in_sizes, int n_in,
                              void* d_out, int out_size, void* d_ws, size_t ws_size,
                              hipStream_t stream) {
  (void)in_sizes; (void)n_in; (void)out_size; (void)ws_size;
  const float* x = (const float*)d_in[0];
  float* out = (float*)d_out;
  float* rn = (float*)d_ws;                                      // 64 KB
  unsigned short* xnT = (unsigned short*)((char*)d_ws + 65536);  // 8 MB bf16

  norms_kernel<<<64, 256, 0, stream>>>(x, rn);
  transpose_kernel<<<1024, 256, 0, stream>>>(x, rn, xnT);
  corr_topk_kernel<<<1024, 512, 0, stream>>>(xnT, out);
}